// Round 6
// baseline (27.460 us; speedup 1.0000x reference)
//
#include <hip/hip_runtime.h>

// Problem constants (from reference setup_inputs)
constexpr int B = 512;
constexpr int S = 16384;
constexpr int NTOK = B * S;                      // 8388608
constexpr int TPT = 32;                          // tokens per thread, 8x int4
constexpr int NBLOCKS = NTOK / TPT / 256;        // 1024
constexpr int NLINES = 32;                       // spread accumulator cachelines
// d_ws layout: u64 acc at byte offset line*64 (one 64B cacheline each),
//              u32 ticket at byte offset NLINES*64. Zeroed per replay.
constexpr int WS_ZERO_BYTES = NLINES * 64 + 64;  // 2112

__global__ __launch_bounds__(256) void mpl_fused(const int* __restrict__ tokens,
                                                 unsigned long long* __restrict__ ws64,
                                                 float* __restrict__ out) {
    const int tid = blockIdx.x * 256 + threadIdx.x;
    const int lane = threadIdx.x & 63;
    const int t0 = tid * TPT;

    int toks[TPT + 1];
    const int4* p = reinterpret_cast<const int4*>(tokens + t0);
#pragma unroll
    for (int v = 0; v < TPT / 4; ++v) {
        int4 x = p[v];
        toks[v * 4 + 0] = x.x;
        toks[v * 4 + 1] = x.y;
        toks[v * 4 + 2] = x.z;
        toks[v * 4 + 3] = x.w;
    }

    // Cross-chunk token: lane i+1's first token via shuffle. Rows are 16384
    // tokens = 8 wave-regions, so only lane 63 can sit at a row boundary; at a
    // row end duplicate our own last token (pair contributes 0 everywhere).
    int nxt = __shfl(toks[0], lane + 1, 64);
    if (lane == 63) {
        const bool rowEnd = ((t0 + TPT) & (S - 1)) == 0;
        nxt = rowEnd ? toks[TPT - 1] : tokens[t0 + TPT];
    }
    toks[TPT] = nxt;

    int rc = 0, hc = 0, mc = 0;
    int qp = 0, pcp = 0, pitp = 0;
#pragma unroll
    for (int j = 0; j <= TPT; ++j) {
        const int t = toks[j];
        const int q = (t + 256) >> 9;            // ts indicator in bit 0 (t<1024)
        const int pit = (t < 128) ? t : 0;       // note-on pitch
        const int pc = pit % 12;
        if (j > 0) {
            rc += (qp ^ q) & 1;                  // time-shift transition
            const int xh = pcp - pc + 11;        // in [0,22]
            hc += (0x00420021u >> xh) & 1;       // pc diff in {-11,-6,6,11}
            const unsigned ym = (unsigned)(pitp - pit + 12);
            mc += (ym > 24u) ? 1 : 0;            // |pitch diff| > 12
        }
        qp = q; pcp = pc; pitp = pit;
    }

    // Wave(64) shuffle reduce: rc,mc packed (wave sums <= 2048 each), hc alone.
    unsigned int pk = (unsigned)rc | ((unsigned)mc << 16);
    unsigned int hh = (unsigned)hc;
#pragma unroll
    for (int off = 32; off > 0; off >>= 1) {
        pk += __shfl_down(pk, off, 64);
        hh += __shfl_down(hh, off, 64);
    }

    __shared__ unsigned int s[2][4];
    __shared__ unsigned int sLast;
    const int wave = threadIdx.x >> 6;
    if ((threadIdx.x & 63) == 0) {
        s[0][wave] = pk;
        s[1][wave] = hh;
    }
    __syncthreads();

    unsigned int* ticket = reinterpret_cast<unsigned int*>(ws64 + NLINES * 8);

    if (threadIdx.x == 0) {
        const unsigned int pks = s[0][0] + s[0][1] + s[0][2] + s[0][3];
        const unsigned int hs  = s[1][0] + s[1][1] + s[1][2] + s[1][3];
        // Pack block sums (each <= 8192 = 2^13) into 21-bit fields; 32 blocks
        // per line -> per-field line sums <= 2^18, no cross-field carry.
        const unsigned long long packed =
            (unsigned long long)(pks & 0xFFFFu) |
            ((unsigned long long)hs << 21) |
            ((unsigned long long)(pks >> 16) << 42);
        const int line = (blockIdx.x & (NLINES - 1)) * 8;  // u64 index, 64B apart
        // Device-scope atomic goes to the cross-XCD coherence point; no fence
        // needed. Using the RETURN VALUE in the ticket operand forces
        // s_waitcnt vmcnt(0) -> data atomic performed before ticket RMW.
        unsigned long long prev = atomicAdd(&ws64[line], packed);
        unsigned int bump = (unsigned int)(prev >> 63);     // always 0
        unsigned int old = atomicAdd(ticket, 1u + bump);
        sLast = (old == (unsigned)(NBLOCKS - 1)) ? 1u : 0u;
    }
    __syncthreads();

    // Last-arriving block: read accumulators coherently, finalize.
    if (sLast && threadIdx.x < 64) {
        unsigned int r = 0, h = 0, m = 0;
        if (threadIdx.x < NLINES) {
            unsigned long long v = atomicAdd(&ws64[threadIdx.x * 8], 0ull);
            r = (unsigned int)(v & 0x1FFFFFull);
            h = (unsigned int)((v >> 21) & 0x1FFFFFull);
            m = (unsigned int)(v >> 42);
        }
#pragma unroll
        for (int off = 16; off > 0; off >>= 1) {
            r += __shfl_down(r, off, 64);
            h += __shfl_down(h, off, 64);
            m += __shfl_down(m, off, 64);
        }
        if (threadIdx.x == 0) {
            const double pairs = (double)B * (double)(S - 1);
            const double all = (double)B * (double)S;
            out[0] = (float)((double)r / pairs + (double)h / all + (double)m / pairs);
        }
    }
}

extern "C" void kernel_launch(void* const* d_in, const int* in_sizes, int n_in,
                              void* d_out, int out_size, void* d_ws, size_t ws_size,
                              hipStream_t stream) {
    const int* tokens = (const int*)d_in[0];
    unsigned long long* ws64 = (unsigned long long*)d_ws;

    hipMemsetAsync(d_ws, 0, WS_ZERO_BYTES, stream);
    mpl_fused<<<NBLOCKS, 256, 0, stream>>>(tokens, ws64, (float*)d_out);
}

// Round 7
// 27.412 us; speedup vs baseline: 1.0018x; 1.0018x over previous
//
#include <hip/hip_runtime.h>

// Problem constants (from reference setup_inputs)
constexpr int B = 512;
constexpr int S = 16384;
constexpr int NTOK = B * S;                      // 8388608
constexpr int TPT = 32;                          // tokens per thread, 8x int4
constexpr int NBLOCKS = NTOK / TPT / 256;        // 1024
// d_ws layout: u64 slots[NBLOCKS] (8 KB), then u32 ticket at byte 8192.
// Slots need NO init (atomicExch overwrites); only the ticket is zeroed.

__global__ void mpl_init(unsigned int* __restrict__ ticket) {
    atomicExch(ticket, 0u);                      // coherence-point write
}

__global__ __launch_bounds__(256) void mpl_fused(const int* __restrict__ tokens,
                                                 unsigned long long* __restrict__ slots,
                                                 unsigned int* __restrict__ ticket,
                                                 float* __restrict__ out) {
    const int tid = blockIdx.x * 256 + threadIdx.x;
    const int lane = threadIdx.x & 63;
    const int t0 = tid * TPT;

    int toks[TPT + 1];
    const int4* p = reinterpret_cast<const int4*>(tokens + t0);
#pragma unroll
    for (int v = 0; v < TPT / 4; ++v) {
        int4 x = p[v];
        toks[v * 4 + 0] = x.x;
        toks[v * 4 + 1] = x.y;
        toks[v * 4 + 2] = x.z;
        toks[v * 4 + 3] = x.w;
    }

    // Cross-chunk token: lane i+1's first token via shuffle. Rows are 16384
    // tokens = 8 wave-regions, so only lane 63 can sit at a row boundary; at a
    // row end duplicate our own last token (pair contributes 0 everywhere).
    int nxt = __shfl(toks[0], lane + 1, 64);
    if (lane == 63) {
        const bool rowEnd = ((t0 + TPT) & (S - 1)) == 0;
        nxt = rowEnd ? toks[TPT - 1] : tokens[t0 + TPT];
    }
    toks[TPT] = nxt;

    int rc = 0, hc = 0, mc = 0;
    int qp = 0, pcp = 0, pitp = 0;
#pragma unroll
    for (int j = 0; j <= TPT; ++j) {
        const int t = toks[j];
        const int q = (t + 256) >> 9;            // ts indicator in bit 0 (t<1024)
        const int pit = (t < 128) ? t : 0;       // note-on pitch
        const int pc = pit % 12;
        if (j > 0) {
            rc += (qp ^ q) & 1;                  // time-shift transition
            const int xh = pcp - pc + 11;        // in [0,22]
            hc += (0x00420021u >> xh) & 1;       // pc diff in {-11,-6,6,11}
            const unsigned ym = (unsigned)(pitp - pit + 12);
            mc += (ym > 24u) ? 1 : 0;            // |pitch diff| > 12
        }
        qp = q; pcp = pc; pitp = pit;
    }

    // Wave(64) shuffle reduce: rc,mc packed (wave sums <= 2048 each), hc alone.
    unsigned int pk = (unsigned)rc | ((unsigned)mc << 16);
    unsigned int hh = (unsigned)hc;
#pragma unroll
    for (int off = 32; off > 0; off >>= 1) {
        pk += __shfl_down(pk, off, 64);
        hh += __shfl_down(hh, off, 64);
    }

    __shared__ unsigned int s[2][4];
    __shared__ unsigned int sLast;
    const int wave = threadIdx.x >> 6;
    if ((threadIdx.x & 63) == 0) {
        s[0][wave] = pk;
        s[1][wave] = hh;
    }
    __syncthreads();

    if (threadIdx.x == 0) {
        const unsigned int pks = s[0][0] + s[0][1] + s[0][2] + s[0][3];
        const unsigned int hs  = s[1][0] + s[1][1] + s[1][2] + s[1][3];
        // Block sums (each <= 8192 = 2^13) packed into 21-bit fields.
        const unsigned long long packed =
            (unsigned long long)(pks & 0xFFFFu) |
            ((unsigned long long)hs << 21) |
            ((unsigned long long)(pks >> 16) << 42);
        // Private slot per block: atomicExch (device-scope, coherence point),
        // no init needed. Keep prev live so the returning form is emitted,
        // then drain vmcnt so the exch is performed before the ticket bump.
        unsigned long long prev = atomicExch(&slots[blockIdx.x], packed);
        asm volatile("" :: "v"((unsigned int)prev), "v"((unsigned int)(prev >> 32)));
        asm volatile("s_waitcnt vmcnt(0)" ::: "memory");
        unsigned int old = atomicAdd(ticket, 1u);
        sLast = (old == (unsigned)(NBLOCKS - 1)) ? 1u : 0u;
    }
    __syncthreads();

    // The 1024th-arriving block: all slots freshly written; read coherently.
    if (sLast) {
        unsigned int r = 0, h = 0, m = 0;
#pragma unroll
        for (int k = 0; k < NBLOCKS / 256; ++k) {
            unsigned long long v = atomicAdd(&slots[threadIdx.x + k * 256], 0ull);
            r += (unsigned int)(v & 0x1FFFFFull);
            h += (unsigned int)((v >> 21) & 0x1FFFFFull);
            m += (unsigned int)(v >> 42);
        }
#pragma unroll
        for (int off = 32; off > 0; off >>= 1) {
            r += __shfl_down(r, off, 64);
            h += __shfl_down(h, off, 64);
            m += __shfl_down(m, off, 64);
        }
        __shared__ unsigned int sf[3][4];
        if ((threadIdx.x & 63) == 0) {
            sf[0][wave] = r; sf[1][wave] = h; sf[2][wave] = m;
        }
        __syncthreads();
        if (threadIdx.x == 0) {
            unsigned int rt = sf[0][0] + sf[0][1] + sf[0][2] + sf[0][3];
            unsigned int ht = sf[1][0] + sf[1][1] + sf[1][2] + sf[1][3];
            unsigned int mt = sf[2][0] + sf[2][1] + sf[2][2] + sf[2][3];
            const double pairs = (double)B * (double)(S - 1);
            const double all = (double)B * (double)S;
            out[0] = (float)((double)rt / pairs + (double)ht / all + (double)mt / pairs);
        }
    }
}

extern "C" void kernel_launch(void* const* d_in, const int* in_sizes, int n_in,
                              void* d_out, int out_size, void* d_ws, size_t ws_size,
                              hipStream_t stream) {
    const int* tokens = (const int*)d_in[0];
    unsigned long long* slots = (unsigned long long*)d_ws;
    unsigned int* ticket = (unsigned int*)((char*)d_ws + NBLOCKS * 8);

    mpl_init<<<1, 1, 0, stream>>>(ticket);
    mpl_fused<<<NBLOCKS, 256, 0, stream>>>(tokens, slots, ticket, (float*)d_out);
}

// Round 8
// 20.749 us; speedup vs baseline: 1.3235x; 1.3211x over previous
//
#include <hip/hip_runtime.h>

// Problem constants (from reference setup_inputs)
constexpr int B = 512;
constexpr int S = 16384;
constexpr int NTOK = B * S;                      // 8388608
constexpr int TPT = 32;                          // tokens per thread, 8x int4
constexpr int NBLOCKS = NTOK / TPT / 256;        // 1024
constexpr int NGROUPS = 32;                      // 32 blocks per group
// d_ws layout:
//   u64 slots[NBLOCKS]                      @ 0       (8 KB, atomicExch -> no init)
//   u32 gticket[NGROUPS] (stride 16 u32s)   @ 8192    (one 64B line each)
//   u32 super                               @ 8192+2048
// Only the 33 ticket words are zeroed per call (by mpl_init).

__global__ void mpl_init(unsigned int* __restrict__ tk) {
    // tk points at gticket base; lanes 0..31 zero group tickets, lane 32 super.
    const int l = threadIdx.x;
    if (l < NGROUPS) atomicExch(&tk[l * 16], 0u);
    else if (l == NGROUPS) atomicExch(&tk[NGROUPS * 16], 0u);
}

__global__ __launch_bounds__(256) void mpl_fused(const int* __restrict__ tokens,
                                                 unsigned long long* __restrict__ slots,
                                                 unsigned int* __restrict__ tk,
                                                 float* __restrict__ out) {
    const int tid = blockIdx.x * 256 + threadIdx.x;
    const int lane = threadIdx.x & 63;
    const int t0 = tid * TPT;

    int toks[TPT + 1];
    const int4* p = reinterpret_cast<const int4*>(tokens + t0);
#pragma unroll
    for (int v = 0; v < TPT / 4; ++v) {
        int4 x = p[v];
        toks[v * 4 + 0] = x.x;
        toks[v * 4 + 1] = x.y;
        toks[v * 4 + 2] = x.z;
        toks[v * 4 + 3] = x.w;
    }

    // Cross-chunk token: lane i+1's first token via shuffle. Rows are 16384
    // tokens = 8 wave-regions, so only lane 63 can sit at a row boundary; at a
    // row end duplicate our own last token (pair contributes 0 everywhere).
    int nxt = __shfl(toks[0], lane + 1, 64);
    if (lane == 63) {
        const bool rowEnd = ((t0 + TPT) & (S - 1)) == 0;
        nxt = rowEnd ? toks[TPT - 1] : tokens[t0 + TPT];
    }
    toks[TPT] = nxt;

    int rc = 0, hc = 0, mc = 0;
    int qp = 0, pcp = 0, pitp = 0;
#pragma unroll
    for (int j = 0; j <= TPT; ++j) {
        const int t = toks[j];
        const int q = (t + 256) >> 9;            // ts indicator in bit 0 (t<1024)
        const int pit = (t < 128) ? t : 0;       // note-on pitch
        const int pc = pit % 12;
        if (j > 0) {
            rc += (qp ^ q) & 1;                  // time-shift transition
            const int xh = pcp - pc + 11;        // in [0,22]
            hc += (0x00420021u >> xh) & 1;       // pc diff in {-11,-6,6,11}
            const unsigned ym = (unsigned)(pitp - pit + 12);
            mc += (ym > 24u) ? 1 : 0;            // |pitch diff| > 12
        }
        qp = q; pcp = pc; pitp = pit;
    }

    // Wave(64) shuffle reduce: rc,mc packed (wave sums <= 2048 each), hc alone.
    unsigned int pk = (unsigned)rc | ((unsigned)mc << 16);
    unsigned int hh = (unsigned)hc;
#pragma unroll
    for (int off = 32; off > 0; off >>= 1) {
        pk += __shfl_down(pk, off, 64);
        hh += __shfl_down(hh, off, 64);
    }

    __shared__ unsigned int s[2][4];
    __shared__ unsigned int sLast;
    const int wave = threadIdx.x >> 6;
    if ((threadIdx.x & 63) == 0) {
        s[0][wave] = pk;
        s[1][wave] = hh;
    }
    __syncthreads();

    if (threadIdx.x == 0) {
        const unsigned int pks = s[0][0] + s[0][1] + s[0][2] + s[0][3];
        const unsigned int hs  = s[1][0] + s[1][1] + s[1][2] + s[1][3];
        // Block sums (each <= 8192 = 2^13) packed into 21-bit fields.
        const unsigned long long packed =
            (unsigned long long)(pks & 0xFFFFu) |
            ((unsigned long long)hs << 21) |
            ((unsigned long long)(pks >> 16) << 42);
        // Private slot per block (atomicExch, coherence point, no init).
        unsigned long long prev = atomicExch(&slots[blockIdx.x], packed);
        asm volatile("" :: "v"((unsigned int)prev), "v"((unsigned int)(prev >> 32)));
        asm volatile("s_waitcnt vmcnt(0)" ::: "memory");
        // Hierarchical ticket: 32 parallel per-group lines (32 RMWs each),
        // then a 32-RMW super line. No single line sees >32 serialized RMWs.
        const int g = blockIdx.x >> 5;           // 32 blocks per group
        unsigned int gold = atomicAdd(&tk[g * 16], 1u);
        unsigned int last = 0;
        if (gold == 31u) {
            unsigned int sold = atomicAdd(&tk[NGROUPS * 16], 1u);
            last = (sold == (unsigned)(NGROUPS - 1)) ? 1u : 0u;
        }
        sLast = last;
    }
    __syncthreads();

    // The globally-last block: all 1024 slots freshly written; read coherently.
    if (sLast) {
        unsigned int r = 0, h = 0, m = 0;
#pragma unroll
        for (int k = 0; k < NBLOCKS / 256; ++k) {
            unsigned long long v = atomicAdd(&slots[threadIdx.x + k * 256], 0ull);
            r += (unsigned int)(v & 0x1FFFFFull);
            h += (unsigned int)((v >> 21) & 0x1FFFFFull);
            m += (unsigned int)(v >> 42);
        }
#pragma unroll
        for (int off = 32; off > 0; off >>= 1) {
            r += __shfl_down(r, off, 64);
            h += __shfl_down(h, off, 64);
            m += __shfl_down(m, off, 64);
        }
        __shared__ unsigned int sf[3][4];
        if ((threadIdx.x & 63) == 0) {
            sf[0][wave] = r; sf[1][wave] = h; sf[2][wave] = m;
        }
        __syncthreads();
        if (threadIdx.x == 0) {
            unsigned int rt = sf[0][0] + sf[0][1] + sf[0][2] + sf[0][3];
            unsigned int ht = sf[1][0] + sf[1][1] + sf[1][2] + sf[1][3];
            unsigned int mt = sf[2][0] + sf[2][1] + sf[2][2] + sf[2][3];
            const double pairs = (double)B * (double)(S - 1);
            const double all = (double)B * (double)S;
            out[0] = (float)((double)rt / pairs + (double)ht / all + (double)mt / pairs);
        }
    }
}

extern "C" void kernel_launch(void* const* d_in, const int* in_sizes, int n_in,
                              void* d_out, int out_size, void* d_ws, size_t ws_size,
                              hipStream_t stream) {
    const int* tokens = (const int*)d_in[0];
    unsigned long long* slots = (unsigned long long*)d_ws;
    unsigned int* tk = (unsigned int*)((char*)d_ws + NBLOCKS * 8);

    mpl_init<<<1, 64, 0, stream>>>(tk);
    mpl_fused<<<NBLOCKS, 256, 0, stream>>>(tokens, slots, tk, (float*)d_out);
}

// Round 10
// 15.604 us; speedup vs baseline: 1.7598x; 1.3297x over previous
//
#include <hip/hip_runtime.h>

// Problem constants (from reference setup_inputs)
constexpr int B = 512;
constexpr int S = 16384;
constexpr int NTOK = B * S;                      // 8388608
constexpr int TPT = 32;                          // tokens per thread, 8x int4
constexpr int NBLOCKS = NTOK / TPT / 256;        // 1024
// d_ws: u64 partials[NBLOCKS] (8 KB), packed rc | hc<<21 | mc<<42
// (block sums <= 8192 = 2^13 each; 21-bit fields -> no overflow).

__global__ __launch_bounds__(256) void mpl_main(const int* __restrict__ tokens,
                                                unsigned long long* __restrict__ partials) {
    const int tid = blockIdx.x * 256 + threadIdx.x;
    const int lane = threadIdx.x & 63;
    const int t0 = tid * TPT;

    int toks[TPT + 1];
    const int4* p = reinterpret_cast<const int4*>(tokens + t0);
#pragma unroll
    for (int v = 0; v < TPT / 4; ++v) {
        int4 x = p[v];
        toks[v * 4 + 0] = x.x;
        toks[v * 4 + 1] = x.y;
        toks[v * 4 + 2] = x.z;
        toks[v * 4 + 3] = x.w;
    }

    // Cross-chunk token: lane i+1's first token via shuffle. Rows are 16384
    // tokens = 8 wave-regions, so only lane 63 can sit at a row boundary; at a
    // row end duplicate our own last token (pair contributes 0 everywhere).
    int nxt = __shfl(toks[0], lane + 1, 64);
    if (lane == 63) {
        const bool rowEnd = ((t0 + TPT) & (S - 1)) == 0;
        nxt = rowEnd ? toks[TPT - 1] : tokens[t0 + TPT];
    }
    toks[TPT] = nxt;

    int rc = 0, hc = 0, mc = 0;
    int qp = 0, pcp = 0, pitp = 0;
#pragma unroll
    for (int j = 0; j <= TPT; ++j) {
        const int t = toks[j];
        const int q = (t + 256) >> 9;            // ts indicator in bit 0 (t<1024)
        const int pit = (t < 128) ? t : 0;       // note-on pitch
        const int pc = pit % 12;
        if (j > 0) {
            rc += (qp ^ q) & 1;                  // time-shift transition
            const int xh = pcp - pc + 11;        // in [0,22]
            hc += (0x00420021u >> xh) & 1;       // pc diff in {-11,-6,6,11}
            const unsigned ym = (unsigned)(pitp - pit + 12);
            mc += (ym > 24u) ? 1 : 0;            // |pitch diff| > 12
        }
        qp = q; pcp = pc; pitp = pit;
    }

    // Wave(64) shuffle reduce: rc,mc packed (wave sums <= 2048 each), hc alone.
    unsigned int pk = (unsigned)rc | ((unsigned)mc << 16);
    unsigned int hh = (unsigned)hc;
#pragma unroll
    for (int off = 32; off > 0; off >>= 1) {
        pk += __shfl_down(pk, off, 64);
        hh += __shfl_down(hh, off, 64);
    }

    __shared__ unsigned int s[2][4];
    const int wave = threadIdx.x >> 6;
    if ((threadIdx.x & 63) == 0) {
        s[0][wave] = pk;
        s[1][wave] = hh;
    }
    __syncthreads();
    if (threadIdx.x == 0) {
        const unsigned int pks = s[0][0] + s[0][1] + s[0][2] + s[0][3];
        const unsigned int hs  = s[1][0] + s[1][1] + s[1][2] + s[1][3];
        // One 8-byte store per block: rc | hc<<21 | mc<<42.
        partials[blockIdx.x] = (unsigned long long)(pks & 0xFFFFu) |
                               ((unsigned long long)hs << 21) |
                               ((unsigned long long)(pks >> 16) << 42);
    }
}

// Single-wave finalizer: 64 lanes x 16 u64 = all 1024 partials in one
// fully-unrolled burst of dwordx4 loads (max MLP, one latency round).
__global__ __launch_bounds__(64) void mpl_reduce(const unsigned long long* __restrict__ partials,
                                                 float* __restrict__ out) {
    const uint4* p4 = reinterpret_cast<const uint4*>(partials);  // 2 u64 per uint4
    unsigned int r = 0, h = 0, m = 0;
#pragma unroll
    for (int k = 0; k < 8; ++k) {                // 8 x uint4 = 16 u64 per lane
        uint4 a = p4[threadIdx.x * 8 + k];
        unsigned long long v0 = (unsigned long long)a.x | ((unsigned long long)a.y << 32);
        unsigned long long v1 = (unsigned long long)a.z | ((unsigned long long)a.w << 32);
        r += (unsigned int)(v0 & 0x1FFFFFull) + (unsigned int)(v1 & 0x1FFFFFull);
        h += (unsigned int)((v0 >> 21) & 0x1FFFFFull) + (unsigned int)((v1 >> 21) & 0x1FFFFFull);
        m += (unsigned int)(v0 >> 42) + (unsigned int)(v1 >> 42);
    }
#pragma unroll
    for (int off = 32; off > 0; off >>= 1) {
        r += __shfl_down(r, off, 64);
        h += __shfl_down(h, off, 64);
        m += __shfl_down(m, off, 64);
    }
    if (threadIdx.x == 0) {
        const double pairs = (double)B * (double)(S - 1);
        const double all = (double)B * (double)S;
        out[0] = (float)((double)r / pairs + (double)h / all + (double)m / pairs);
    }
}

extern "C" void kernel_launch(void* const* d_in, const int* in_sizes, int n_in,
                              void* d_out, int out_size, void* d_ws, size_t ws_size,
                              hipStream_t stream) {
    const int* tokens = (const int*)d_in[0];
    unsigned long long* partials = (unsigned long long*)d_ws;  // 8 KB

    mpl_main<<<NBLOCKS, 256, 0, stream>>>(tokens, partials);
    mpl_reduce<<<1, 64, 0, stream>>>(partials, (float*)d_out);
}